// Round 1
// baseline (888.299 us; speedup 1.0000x reference)
//
#include <hip/hip_runtime.h>
#include <math.h>

#define FDIM 128
#define F3   384

static constexpr int K1_R = 8;    // rows per block, context net
static constexpr int K2_R = 8;    // rows per block, v@Wmix ctx
static constexpr int K4_R = 4;    // rows per block, epilogue
static constexpr int CHUNK = 64;  // edges per LDS prefetch chunk in k3

typedef float vf4 __attribute__((ext_vector_type(4)));

__device__ __forceinline__ vf4 fma4(vf4 a, vf4 b, vf4 c) {
    vf4 r;
    r[0] = fmaf(a[0], b[0], c[0]);
    r[1] = fmaf(a[1], b[1], c[1]);
    r[2] = fmaf(a[2], b[2], c[2]);
    r[3] = fmaf(a[3], b[3], c[3]);
    return r;
}
__device__ __forceinline__ vf4 fma4s(vf4 a, float s, vf4 c) {
    vf4 r;
    r[0] = fmaf(a[0], s, c[0]);
    r[1] = fmaf(a[1], s, c[1]);
    r[2] = fmaf(a[2], s, c[2]);
    r[3] = fmaf(a[3], s, c[3]);
    return r;
}

// ---------------------------------------------------------------------------
// Kernel 0: segment offsets. seg[n] = lower_bound(idx_i, n), seg[N] = E.
// ---------------------------------------------------------------------------
__global__ __launch_bounds__(256) void k0_seg(
    const int* __restrict__ idx_i, int* __restrict__ seg, int E, int N)
{
    int n = blockIdx.x * 256 + threadIdx.x;
    if (n > N) return;
    if (n == N) { seg[n] = E; return; }
    int lo = 0, hi = E;
    while (lo < hi) {
        int m = (lo + hi) >> 1;
        if (idx_i[m] < n) lo = m + 1; else hi = m;
    }
    seg[n] = lo;
}

// ---------------------------------------------------------------------------
// Kernel 1: X = silu(H @ W1 + b1) @ W2 + b2        [N, 3F]
// ---------------------------------------------------------------------------
__global__ __launch_bounds__(128) void k1_ctxnet(
    const float* __restrict__ H,  const float* __restrict__ W1,
    const float* __restrict__ b1, const float* __restrict__ W2,
    const float* __restrict__ b2, float* __restrict__ X, int N)
{
    __shared__ float sH[K1_R][FDIM];
    __shared__ float sT[K1_R][FDIM];
    const int f  = threadIdx.x;
    const int n0 = blockIdx.x * K1_R;

    for (int r = 0; r < K1_R; ++r) {
        int n = n0 + r;
        sH[r][f] = (n < N) ? H[(size_t)n * FDIM + f] : 0.f;
    }
    __syncthreads();

    float acc[K1_R];
    #pragma unroll
    for (int r = 0; r < K1_R; ++r) acc[r] = 0.f;
    #pragma unroll 4
    for (int a = 0; a < FDIM; ++a) {
        float w = W1[a * FDIM + f];
        #pragma unroll
        for (int r = 0; r < K1_R; ++r) acc[r] = fmaf(sH[r][a], w, acc[r]);
    }
    float bb = b1[f];
    #pragma unroll
    for (int r = 0; r < K1_R; ++r) {
        float t = acc[r] + bb;
        sT[r][f] = t / (1.f + expf(-t));   // silu
    }
    __syncthreads();

    float a0[K1_R], a1[K1_R], a2[K1_R];
    #pragma unroll
    for (int r = 0; r < K1_R; ++r) { a0[r] = 0.f; a1[r] = 0.f; a2[r] = 0.f; }
    #pragma unroll 4
    for (int a = 0; a < FDIM; ++a) {
        float w0 = W2[a * F3 + f];
        float w1 = W2[a * F3 + FDIM + f];
        float w2 = W2[a * F3 + 2 * FDIM + f];
        #pragma unroll
        for (int r = 0; r < K1_R; ++r) {
            float t = sT[r][a];
            a0[r] = fmaf(t, w0, a0[r]);
            a1[r] = fmaf(t, w1, a1[r]);
            a2[r] = fmaf(t, w2, a2[r]);
        }
    }
    float c0 = b2[f], c1 = b2[FDIM + f], c2 = b2[2 * FDIM + f];
    for (int r = 0; r < K1_R; ++r) {
        int n = n0 + r;
        if (n < N) {
            X[(size_t)n * F3 + f]            = a0[r] + c0;
            X[(size_t)n * F3 + FDIM + f]     = a1[r] + c1;
            X[(size_t)n * F3 + 2 * FDIM + f] = a2[r] + c2;
        }
    }
}

// ---------------------------------------------------------------------------
// Kernel 2: ctx[n,f] = sum_d (v[n,d,:] @ Wmix[:, f]) * (v[n,d,:] @ Wmix[:, F+f])
// ---------------------------------------------------------------------------
__global__ __launch_bounds__(128) void k2_ctx(
    const float* __restrict__ v, const float* __restrict__ Wmix,
    float* __restrict__ ctx, int N)
{
    __shared__ float sv[3][K2_R][FDIM];
    const int f  = threadIdx.x;
    const int n0 = blockIdx.x * K2_R;

    for (int r = 0; r < K2_R; ++r) {
        int n = n0 + r;
        for (int d = 0; d < 3; ++d)
            sv[d][r][f] = (n < N) ? v[((size_t)n * 3 + d) * FDIM + f] : 0.f;
    }
    __syncthreads();

    float cacc[K2_R];
    #pragma unroll
    for (int r = 0; r < K2_R; ++r) cacc[r] = 0.f;

    for (int d = 0; d < 3; ++d) {
        float aV[K2_R], aW[K2_R];
        #pragma unroll
        for (int r = 0; r < K2_R; ++r) { aV[r] = 0.f; aW[r] = 0.f; }
        #pragma unroll 4
        for (int a = 0; a < FDIM; ++a) {
            float w0 = Wmix[a * (2 * FDIM) + f];
            float w1 = Wmix[a * (2 * FDIM) + FDIM + f];
            #pragma unroll
            for (int r = 0; r < K2_R; ++r) {
                float t = sv[d][r][a];
                aV[r] = fmaf(t, w0, aV[r]);
                aW[r] = fmaf(t, w1, aW[r]);
            }
        }
        #pragma unroll
        for (int r = 0; r < K2_R; ++r) cacc[r] = fmaf(aV[r], aW[r], cacc[r]);
    }
    for (int r = 0; r < K2_R; ++r) {
        int n = n0 + r;
        if (n < N) ctx[(size_t)n * FDIM + f] = cacc[r];
    }
}

// ---------------------------------------------------------------------------
// Kernel 3: edge gather + segment reduction, float4 edition.
// Block per atom. 8 edge-groups of 32 lanes; each lane owns 4 channels.
// Per edge a group issues 9 dwordx4 loads (vs 36 dword in the scalar
// version) -> 4x fewer vmem requests, 4x more bytes in flight per wave.
// idx_j / dir staged in LDS per 64-edge chunk so gather addresses never
// sit behind a dependent index load. Wij nontemporal (streamed once).
// Group partials combined through a 16KB LDS tile.
// ---------------------------------------------------------------------------
__global__ __launch_bounds__(256) void k3_edges(
    const float* __restrict__ X, const float* __restrict__ V,
    const float* __restrict__ Wij, const float* __restrict__ dir_ij,
    const int* __restrict__ seg, const int* __restrict__ idx_j,
    float* __restrict__ dh, float* __restrict__ dv)
{
    const int n   = blockIdx.x;
    const int tid = threadIdx.x;
    const int g   = tid >> 5;          // edge group 0..7
    const int l   = tid & 31;          // lane in group; owns channels 4l..4l+3

    __shared__ int   sj[CHUNK];
    __shared__ float sd[CHUNK][4];
    __shared__ vf4   sacc[8][4][32];   // 16 KB: [group][acc][lane]

    const int e0 = seg[n];
    const int e1 = seg[n + 1];

    vf4 adh = {0.f, 0.f, 0.f, 0.f};
    vf4 a0  = {0.f, 0.f, 0.f, 0.f};
    vf4 a1  = {0.f, 0.f, 0.f, 0.f};
    vf4 a2  = {0.f, 0.f, 0.f, 0.f};

    for (int base = e0; base < e1; base += CHUNK) {
        const int cnt = (e1 - base < CHUNK) ? (e1 - base) : CHUNK;
        if (tid < cnt) sj[tid] = idx_j[base + tid];
        for (int t = tid; t < 3 * cnt; t += 256)
            sd[t / 3][t % 3] = dir_ij[(size_t)base * 3 + t];
        __syncthreads();

        int kk = g;
        // 2 edges in flight per group (18 dwordx4 outstanding)
        for (; kk + 8 < cnt; kk += 16) {
            const int eA = base + kk,     jA = sj[kk];
            const int eB = base + kk + 8, jB = sj[kk + 8];
            const vf4* wA = (const vf4*)(Wij + (size_t)eA * F3);
            const vf4* xA = (const vf4*)(X   + (size_t)jA * F3);
            const vf4* qA = (const vf4*)(V   + (size_t)jA * F3);
            const vf4* wB = (const vf4*)(Wij + (size_t)eB * F3);
            const vf4* xB = (const vf4*)(X   + (size_t)jB * F3);
            const vf4* qB = (const vf4*)(V   + (size_t)jB * F3);

            vf4 wA0 = __builtin_nontemporal_load(wA + l);
            vf4 wA1 = __builtin_nontemporal_load(wA + 32 + l);
            vf4 wA2 = __builtin_nontemporal_load(wA + 64 + l);
            vf4 xA0 = xA[l], xA1 = xA[32 + l], xA2 = xA[64 + l];
            vf4 vA0 = qA[l], vA1 = qA[32 + l], vA2 = qA[64 + l];
            vf4 wB0 = __builtin_nontemporal_load(wB + l);
            vf4 wB1 = __builtin_nontemporal_load(wB + 32 + l);
            vf4 wB2 = __builtin_nontemporal_load(wB + 64 + l);
            vf4 xB0 = xB[l], xB1 = xB[32 + l], xB2 = xB[64 + l];
            vf4 vB0 = qB[l], vB1 = qB[32 + l], vB2 = qB[64 + l];

            const float dA0 = sd[kk][0],     dA1 = sd[kk][1],     dA2 = sd[kk][2];
            const float dB0 = sd[kk + 8][0], dB1 = sd[kk + 8][1], dB2 = sd[kk + 8][2];

            adh = fma4(wA0, xA0, adh);
            {
                vf4 r = wA1 * xA1, s = wA2 * xA2;
                a0 = fma4s(r, dA0, fma4(s, vA0, a0));
                a1 = fma4s(r, dA1, fma4(s, vA1, a1));
                a2 = fma4s(r, dA2, fma4(s, vA2, a2));
            }
            adh = fma4(wB0, xB0, adh);
            {
                vf4 r = wB1 * xB1, s = wB2 * xB2;
                a0 = fma4s(r, dB0, fma4(s, vB0, a0));
                a1 = fma4s(r, dB1, fma4(s, vB1, a1));
                a2 = fma4s(r, dB2, fma4(s, vB2, a2));
            }
        }
        for (; kk < cnt; kk += 8) {
            const int e = base + kk, j = sj[kk];
            const vf4* w = (const vf4*)(Wij + (size_t)e * F3);
            const vf4* x = (const vf4*)(X   + (size_t)j * F3);
            const vf4* q = (const vf4*)(V   + (size_t)j * F3);
            vf4 w0 = __builtin_nontemporal_load(w + l);
            vf4 w1 = __builtin_nontemporal_load(w + 32 + l);
            vf4 w2 = __builtin_nontemporal_load(w + 64 + l);
            vf4 x0 = x[l], x1 = x[32 + l], x2 = x[64 + l];
            vf4 v0 = q[l], v1 = q[32 + l], v2 = q[64 + l];
            const float d0 = sd[kk][0], d1 = sd[kk][1], d2 = sd[kk][2];

            adh = fma4(w0, x0, adh);
            vf4 r = w1 * x1, s = w2 * x2;
            a0 = fma4s(r, d0, fma4(s, v0, a0));
            a1 = fma4s(r, d1, fma4(s, v1, a1));
            a2 = fma4s(r, d2, fma4(s, v2, a2));
        }
        __syncthreads();
    }

    // combine the 8 group partials
    sacc[g][0][l] = adh;
    sacc[g][1][l] = a0;
    sacc[g][2][l] = a1;
    sacc[g][3][l] = a2;
    __syncthreads();

    if (tid < 128) {
        const int c  = tid >> 5;   // which accumulator
        const int ll = tid & 31;   // which channel quad
        vf4 s = sacc[0][c][ll];
        #pragma unroll
        for (int gg = 1; gg < 8; ++gg) s += sacc[gg][c][ll];
        if (c == 0)
            ((vf4*)(dh + (size_t)n * FDIM))[ll] = s;
        else
            ((vf4*)(dv + (size_t)n * F3))[(c - 1) * 32 + ll] = s;
    }
}

// ---------------------------------------------------------------------------
// Kernel 4: epilogue.
// q  = LN(h + dh@Whr + (dh@Whf)*ctx) * gamma + beta
// mu = (v*(1+dh.Wvr) + dv) / rms
// ---------------------------------------------------------------------------
__device__ inline float block_reduce_sum_128(float val, float* tmp) {
    #pragma unroll
    for (int o = 32; o > 0; o >>= 1) val += __shfl_down(val, o, 64);
    const int tid = threadIdx.x;
    if ((tid & 63) == 0) tmp[tid >> 6] = val;
    __syncthreads();
    float r = tmp[0] + tmp[1];
    __syncthreads();
    return r;
}

__global__ __launch_bounds__(128) void k4_epilogue(
    const float* __restrict__ h,   const float* __restrict__ v,
    const float* __restrict__ dh,  const float* __restrict__ dv,
    const float* __restrict__ ctx,
    const float* __restrict__ Whr, const float* __restrict__ Whf,
    const float* __restrict__ Wvr,
    const float* __restrict__ gamma, const float* __restrict__ beta,
    float* __restrict__ q, float* __restrict__ mu, int N)
{
    __shared__ float sdh[K4_R][FDIM];
    __shared__ float sred[2];
    const int f  = threadIdx.x;
    const int n0 = blockIdx.x * K4_R;

    for (int r = 0; r < K4_R; ++r) {
        int n = n0 + r;
        sdh[r][f] = (n < N) ? dh[(size_t)n * FDIM + f] : 0.f;
    }
    __syncthreads();

    float accR[K4_R], accF[K4_R];
    #pragma unroll
    for (int r = 0; r < K4_R; ++r) { accR[r] = 0.f; accF[r] = 0.f; }
    #pragma unroll 4
    for (int a = 0; a < FDIM; ++a) {
        float wr = Whr[a * FDIM + f];
        float wf = Whf[a * FDIM + f];
        #pragma unroll
        for (int r = 0; r < K4_R; ++r) {
            accR[r] = fmaf(sdh[r][a], wr, accR[r]);
            accF[r] = fmaf(sdh[r][a], wf, accF[r]);
        }
    }

    const float wv = Wvr[f];
    const float g  = gamma[f];
    const float bt = beta[f];

    for (int r = 0; r < K4_R; ++r) {
        int n = n0 + r;
        if (n >= N) break;   // uniform across block

        float s = block_reduce_sum_128(sdh[r][f] * wv, sred);

        float u    = h[(size_t)n * FDIM + f] + accR[r] + accF[r] * ctx[(size_t)n * FDIM + f];
        float mean = block_reduce_sum_128(u, sred) * (1.f / 128.f);
        float dlt  = u - mean;
        float var  = block_reduce_sum_128(dlt * dlt, sred) * (1.f / 128.f);
        q[(size_t)n * FDIM + f] = dlt * rsqrtf(var + 1e-5f) * g + bt;

        float sc = 1.f + s;
        float x0 = fmaf(v[((size_t)n * 3 + 0) * FDIM + f], sc, dv[(size_t)n * F3 + f]);
        float x1 = fmaf(v[((size_t)n * 3 + 1) * FDIM + f], sc, dv[(size_t)n * F3 + FDIM + f]);
        float x2 = fmaf(v[((size_t)n * 3 + 2) * FDIM + f], sc, dv[(size_t)n * F3 + 2 * FDIM + f]);
        float sq  = x0 * x0 + x1 * x1 + x2 * x2;
        float tot = block_reduce_sum_128(sq, sred) * (1.f / 128.f);
        float inv = rsqrtf(tot + 1e-8f);
        mu[((size_t)n * 3 + 0) * FDIM + f] = x0 * inv;
        mu[((size_t)n * 3 + 1) * FDIM + f] = x1 * inv;
        mu[((size_t)n * 3 + 2) * FDIM + f] = x2 * inv;
    }
}

// ---------------------------------------------------------------------------
extern "C" void kernel_launch(void* const* d_in, const int* in_sizes, int n_in,
                              void* d_out, int out_size, void* d_ws, size_t ws_size,
                              hipStream_t stream)
{
    const float* h     = (const float*)d_in[0];
    const float* v     = (const float*)d_in[1];
    const float* H     = (const float*)d_in[2];
    const float* V     = (const float*)d_in[3];
    const float* Wij   = (const float*)d_in[4];
    const float* dir   = (const float*)d_in[5];
    const float* W1    = (const float*)d_in[6];
    const float* b1    = (const float*)d_in[7];
    const float* W2    = (const float*)d_in[8];
    const float* b2    = (const float*)d_in[9];
    const float* Wmix  = (const float*)d_in[10];
    const float* Whr   = (const float*)d_in[11];
    const float* Whf   = (const float*)d_in[12];
    const float* Wvr   = (const float*)d_in[13];
    const float* gamma = (const float*)d_in[14];
    const float* beta  = (const float*)d_in[15];
    const int*   idx_i = (const int*)d_in[16];
    const int*   idx_j = (const int*)d_in[17];

    const int N = in_sizes[0] / FDIM;
    const int E = in_sizes[16];

    float* ws  = (float*)d_ws;
    float* X   = ws;                         // N*384
    float* ctx = X   + (size_t)N * F3;       // N*128
    float* dh  = ctx + (size_t)N * FDIM;     // N*128
    float* dv  = dh  + (size_t)N * FDIM;     // N*384
    int*   seg = (int*)(dv + (size_t)N * F3);// N+1

    float* q   = (float*)d_out;              // N*128
    float* mu  = q + (size_t)N * FDIM;       // N*384

    hipLaunchKernelGGL(k0_seg, dim3((N + 256) / 256), dim3(256), 0, stream,
                       idx_i, seg, E, N);
    hipLaunchKernelGGL(k1_ctxnet, dim3((N + K1_R - 1) / K1_R), dim3(128), 0, stream,
                       H, W1, b1, W2, b2, X, N);
    hipLaunchKernelGGL(k2_ctx, dim3((N + K2_R - 1) / K2_R), dim3(128), 0, stream,
                       v, Wmix, ctx, N);
    hipLaunchKernelGGL(k3_edges, dim3(N), dim3(256), 0, stream,
                       X, V, Wij, dir, seg, idx_j, dh, dv);
    hipLaunchKernelGGL(k4_epilogue, dim3((N + K4_R - 1) / K4_R), dim3(128), 0, stream,
                       h, v, dh, dv, ctx, Whr, Whf, Wvr, gamma, beta, q, mu, N);
}

// Round 2
// 886.920 us; speedup vs baseline: 1.0016x; 1.0016x over previous
//
#include <hip/hip_runtime.h>
#include <math.h>

#define FDIM 128
#define F3   384

static constexpr int K1_R = 8;    // rows per block, fused context net + mix
static constexpr int K4_R = 4;    // rows per block, epilogue
static constexpr int CHUNK = 64;  // edges per LDS prefetch chunk in k3

typedef float vf4 __attribute__((ext_vector_type(4)));

__device__ __forceinline__ vf4 fma4(vf4 a, vf4 b, vf4 c) {
    vf4 r;
    r[0] = fmaf(a[0], b[0], c[0]);
    r[1] = fmaf(a[1], b[1], c[1]);
    r[2] = fmaf(a[2], b[2], c[2]);
    r[3] = fmaf(a[3], b[3], c[3]);
    return r;
}
__device__ __forceinline__ vf4 fma4s(vf4 a, float s, vf4 c) {
    vf4 r;
    r[0] = fmaf(a[0], s, c[0]);
    r[1] = fmaf(a[1], s, c[1]);
    r[2] = fmaf(a[2], s, c[2]);
    r[3] = fmaf(a[3], s, c[3]);
    return r;
}

// ---------------------------------------------------------------------------
// Kernel 0: segment offsets. seg[n] = lower_bound(idx_i, n), seg[N] = E.
// ---------------------------------------------------------------------------
__global__ __launch_bounds__(256) void k0_seg(
    const int* __restrict__ idx_i, int* __restrict__ seg, int E, int N)
{
    int n = blockIdx.x * 256 + threadIdx.x;
    if (n > N) return;
    if (n == N) { seg[n] = E; return; }
    int lo = 0, hi = E;
    while (lo < hi) {
        int m = (lo + hi) >> 1;
        if (idx_i[m] < n) lo = m + 1; else hi = m;
    }
    seg[n] = lo;
}

// ---------------------------------------------------------------------------
// Kernel 12: fused context net + vector mix.
//   X   = silu(H @ W1 + b1) @ W2 + b2                       [N, 3F]
//   ctx = sum_d (v[:,d,:] @ Wmix[:, :F]) * (v[:,d,:] @ Wmix[:, F:])  [N, F]
// One dispatch instead of two; shared 8-row block staging.
// ---------------------------------------------------------------------------
__global__ __launch_bounds__(128) void k12_ctxnet_mix(
    const float* __restrict__ H,  const float* __restrict__ W1,
    const float* __restrict__ b1, const float* __restrict__ W2,
    const float* __restrict__ b2,
    const float* __restrict__ v,  const float* __restrict__ Wmix,
    float* __restrict__ X, float* __restrict__ ctx, int N)
{
    __shared__ float sH[K1_R][FDIM];
    __shared__ float sT[K1_R][FDIM];
    __shared__ float sv[3][K1_R][FDIM];
    const int f  = threadIdx.x;
    const int n0 = blockIdx.x * K1_R;

    for (int r = 0; r < K1_R; ++r) {
        int n = n0 + r;
        sH[r][f] = (n < N) ? H[(size_t)n * FDIM + f] : 0.f;
        for (int d = 0; d < 3; ++d)
            sv[d][r][f] = (n < N) ? v[((size_t)n * 3 + d) * FDIM + f] : 0.f;
    }
    __syncthreads();

    // ---- layer 1 + silu -> sT
    float acc[K1_R];
    #pragma unroll
    for (int r = 0; r < K1_R; ++r) acc[r] = 0.f;
    #pragma unroll 4
    for (int a = 0; a < FDIM; ++a) {
        float w = W1[a * FDIM + f];
        #pragma unroll
        for (int r = 0; r < K1_R; ++r) acc[r] = fmaf(sH[r][a], w, acc[r]);
    }
    float bb = b1[f];
    #pragma unroll
    for (int r = 0; r < K1_R; ++r) {
        float t = acc[r] + bb;
        sT[r][f] = t / (1.f + expf(-t));   // silu
    }
    __syncthreads();

    // ---- layer 2 -> X
    float a0[K1_R], a1[K1_R], a2[K1_R];
    #pragma unroll
    for (int r = 0; r < K1_R; ++r) { a0[r] = 0.f; a1[r] = 0.f; a2[r] = 0.f; }
    #pragma unroll 4
    for (int a = 0; a < FDIM; ++a) {
        float w0 = W2[a * F3 + f];
        float w1 = W2[a * F3 + FDIM + f];
        float w2 = W2[a * F3 + 2 * FDIM + f];
        #pragma unroll
        for (int r = 0; r < K1_R; ++r) {
            float t = sT[r][a];
            a0[r] = fmaf(t, w0, a0[r]);
            a1[r] = fmaf(t, w1, a1[r]);
            a2[r] = fmaf(t, w2, a2[r]);
        }
    }
    float c0 = b2[f], c1 = b2[FDIM + f], c2 = b2[2 * FDIM + f];
    for (int r = 0; r < K1_R; ++r) {
        int n = n0 + r;
        if (n < N) {
            X[(size_t)n * F3 + f]            = a0[r] + c0;
            X[(size_t)n * F3 + FDIM + f]     = a1[r] + c1;
            X[(size_t)n * F3 + 2 * FDIM + f] = a2[r] + c2;
        }
    }

    // ---- vector mix -> ctx
    float cacc[K1_R];
    #pragma unroll
    for (int r = 0; r < K1_R; ++r) cacc[r] = 0.f;
    for (int d = 0; d < 3; ++d) {
        float aV[K1_R], aW[K1_R];
        #pragma unroll
        for (int r = 0; r < K1_R; ++r) { aV[r] = 0.f; aW[r] = 0.f; }
        #pragma unroll 4
        for (int a = 0; a < FDIM; ++a) {
            float w0 = Wmix[a * (2 * FDIM) + f];
            float w1 = Wmix[a * (2 * FDIM) + FDIM + f];
            #pragma unroll
            for (int r = 0; r < K1_R; ++r) {
                float t = sv[d][r][a];
                aV[r] = fmaf(t, w0, aV[r]);
                aW[r] = fmaf(t, w1, aW[r]);
            }
        }
        #pragma unroll
        for (int r = 0; r < K1_R; ++r) cacc[r] = fmaf(aV[r], aW[r], cacc[r]);
    }
    for (int r = 0; r < K1_R; ++r) {
        int n = n0 + r;
        if (n < N) ctx[(size_t)n * FDIM + f] = cacc[r];
    }
}

// ---------------------------------------------------------------------------
// Kernel 3: edge gather + segment reduction, float4, bandwidth-ordered.
// Block per atom; 8 edge-groups of 32 lanes, each lane owns 4 channels.
// Cache-served X/V gathers issued BEFORE the nontemporal Wij stream so
// their L3-hit latency overlaps the HBM stream latency. 2 edges in
// flight per group; group partials combined through a 16 KB LDS tile.
// ---------------------------------------------------------------------------
__global__ __launch_bounds__(256) void k3_edges(
    const float* __restrict__ X, const float* __restrict__ V,
    const float* __restrict__ Wij, const float* __restrict__ dir_ij,
    const int* __restrict__ seg, const int* __restrict__ idx_j,
    float* __restrict__ dh, float* __restrict__ dv)
{
    const int n   = blockIdx.x;
    const int tid = threadIdx.x;
    const int g   = tid >> 5;          // edge group 0..7
    const int l   = tid & 31;          // lane in group; owns channels 4l..4l+3

    __shared__ int   sj[CHUNK];
    __shared__ float sd[CHUNK][4];
    __shared__ vf4   sacc[8][4][32];   // 16 KB: [group][acc][lane]

    const int e0 = seg[n];
    const int e1 = seg[n + 1];

    vf4 adh = {0.f, 0.f, 0.f, 0.f};
    vf4 a0  = {0.f, 0.f, 0.f, 0.f};
    vf4 a1  = {0.f, 0.f, 0.f, 0.f};
    vf4 a2  = {0.f, 0.f, 0.f, 0.f};

    for (int base = e0; base < e1; base += CHUNK) {
        const int cnt = (e1 - base < CHUNK) ? (e1 - base) : CHUNK;
        if (tid < cnt) sj[tid] = idx_j[base + tid];
        for (int t = tid; t < 3 * cnt; t += 256)
            sd[t / 3][t % 3] = dir_ij[(size_t)base * 3 + t];
        __syncthreads();

        int kk = g;
        for (; kk + 8 < cnt; kk += 16) {
            const int eA = base + kk,     jA = sj[kk];
            const int eB = base + kk + 8, jB = sj[kk + 8];
            const vf4* wA = (const vf4*)(Wij + (size_t)eA * F3);
            const vf4* xA = (const vf4*)(X   + (size_t)jA * F3);
            const vf4* qA = (const vf4*)(V   + (size_t)jA * F3);
            const vf4* wB = (const vf4*)(Wij + (size_t)eB * F3);
            const vf4* xB = (const vf4*)(X   + (size_t)jB * F3);
            const vf4* qB = (const vf4*)(V   + (size_t)jB * F3);

            // gathers first (L3-served), stream last (HBM)
            vf4 xA0 = xA[l], xA1 = xA[32 + l], xA2 = xA[64 + l];
            vf4 vA0 = qA[l], vA1 = qA[32 + l], vA2 = qA[64 + l];
            vf4 xB0 = xB[l], xB1 = xB[32 + l], xB2 = xB[64 + l];
            vf4 vB0 = qB[l], vB1 = qB[32 + l], vB2 = qB[64 + l];
            vf4 wA0 = __builtin_nontemporal_load(wA + l);
            vf4 wA1 = __builtin_nontemporal_load(wA + 32 + l);
            vf4 wA2 = __builtin_nontemporal_load(wA + 64 + l);
            vf4 wB0 = __builtin_nontemporal_load(wB + l);
            vf4 wB1 = __builtin_nontemporal_load(wB + 32 + l);
            vf4 wB2 = __builtin_nontemporal_load(wB + 64 + l);

            const float dA0 = sd[kk][0],     dA1 = sd[kk][1],     dA2 = sd[kk][2];
            const float dB0 = sd[kk + 8][0], dB1 = sd[kk + 8][1], dB2 = sd[kk + 8][2];

            adh = fma4(wA0, xA0, adh);
            {
                vf4 r = wA1 * xA1, s = wA2 * xA2;
                a0 = fma4s(r, dA0, fma4(s, vA0, a0));
                a1 = fma4s(r, dA1, fma4(s, vA1, a1));
                a2 = fma4s(r, dA2, fma4(s, vA2, a2));
            }
            adh = fma4(wB0, xB0, adh);
            {
                vf4 r = wB1 * xB1, s = wB2 * xB2;
                a0 = fma4s(r, dB0, fma4(s, vB0, a0));
                a1 = fma4s(r, dB1, fma4(s, vB1, a1));
                a2 = fma4s(r, dB2, fma4(s, vB2, a2));
            }
        }
        for (; kk < cnt; kk += 8) {
            const int e = base + kk, j = sj[kk];
            const vf4* w = (const vf4*)(Wij + (size_t)e * F3);
            const vf4* x = (const vf4*)(X   + (size_t)j * F3);
            const vf4* q = (const vf4*)(V   + (size_t)j * F3);
            vf4 x0 = x[l], x1 = x[32 + l], x2 = x[64 + l];
            vf4 v0 = q[l], v1 = q[32 + l], v2 = q[64 + l];
            vf4 w0 = __builtin_nontemporal_load(w + l);
            vf4 w1 = __builtin_nontemporal_load(w + 32 + l);
            vf4 w2 = __builtin_nontemporal_load(w + 64 + l);
            const float d0 = sd[kk][0], d1 = sd[kk][1], d2 = sd[kk][2];

            adh = fma4(w0, x0, adh);
            vf4 r = w1 * x1, s = w2 * x2;
            a0 = fma4s(r, d0, fma4(s, v0, a0));
            a1 = fma4s(r, d1, fma4(s, v1, a1));
            a2 = fma4s(r, d2, fma4(s, v2, a2));
        }
        __syncthreads();
    }

    // combine the 8 group partials
    sacc[g][0][l] = adh;
    sacc[g][1][l] = a0;
    sacc[g][2][l] = a1;
    sacc[g][3][l] = a2;
    __syncthreads();

    if (tid < 128) {
        const int c  = tid >> 5;   // which accumulator
        const int ll = tid & 31;   // which channel quad
        vf4 s = sacc[0][c][ll];
        #pragma unroll
        for (int gg = 1; gg < 8; ++gg) s += sacc[gg][c][ll];
        if (c == 0)
            ((vf4*)(dh + (size_t)n * FDIM))[ll] = s;
        else
            ((vf4*)(dv + (size_t)n * F3))[(c - 1) * 32 + ll] = s;
    }
}

// ---------------------------------------------------------------------------
// Kernel 4: epilogue, paired block reductions (2 rounds instead of 4).
// q  = LN(h + dh@Whr + (dh@Whf)*ctx) * gamma + beta
// mu = (v*(1+dh.Wvr) + dv) / rms
// ---------------------------------------------------------------------------
__device__ __forceinline__ void block_reduce2_128(float& a, float& b, float* tmp) {
    #pragma unroll
    for (int o = 32; o > 0; o >>= 1) {
        a += __shfl_down(a, o, 64);
        b += __shfl_down(b, o, 64);
    }
    const int tid = threadIdx.x;
    if ((tid & 63) == 0) {
        tmp[(tid >> 6) * 2]     = a;
        tmp[(tid >> 6) * 2 + 1] = b;
    }
    __syncthreads();
    a = tmp[0] + tmp[2];
    b = tmp[1] + tmp[3];
    __syncthreads();
}

__global__ __launch_bounds__(128) void k4_epilogue(
    const float* __restrict__ h,   const float* __restrict__ v,
    const float* __restrict__ dh,  const float* __restrict__ dv,
    const float* __restrict__ ctx,
    const float* __restrict__ Whr, const float* __restrict__ Whf,
    const float* __restrict__ Wvr,
    const float* __restrict__ gamma, const float* __restrict__ beta,
    float* __restrict__ q, float* __restrict__ mu, int N)
{
    __shared__ float sdh[K4_R][FDIM];
    __shared__ float sred[4];
    const int f  = threadIdx.x;
    const int n0 = blockIdx.x * K4_R;

    for (int r = 0; r < K4_R; ++r) {
        int n = n0 + r;
        sdh[r][f] = (n < N) ? dh[(size_t)n * FDIM + f] : 0.f;
    }
    __syncthreads();

    float accR[K4_R], accF[K4_R];
    #pragma unroll
    for (int r = 0; r < K4_R; ++r) { accR[r] = 0.f; accF[r] = 0.f; }
    #pragma unroll 4
    for (int a = 0; a < FDIM; ++a) {
        float wr = Whr[a * FDIM + f];
        float wf = Whf[a * FDIM + f];
        #pragma unroll
        for (int r = 0; r < K4_R; ++r) {
            accR[r] = fmaf(sdh[r][a], wr, accR[r]);
            accF[r] = fmaf(sdh[r][a], wf, accF[r]);
        }
    }

    const float wv = Wvr[f];
    const float g  = gamma[f];
    const float bt = beta[f];

    for (int r = 0; r < K4_R; ++r) {
        int n = n0 + r;
        if (n >= N) break;   // uniform across block

        float u  = h[(size_t)n * FDIM + f] + accR[r]
                 + accF[r] * ctx[(size_t)n * FDIM + f];
        float su = u;
        float s  = sdh[r][f] * wv;
        block_reduce2_128(su, s, sred);          // round 1: Σu and Σ dh·wv

        float mean = su * (1.f / 128.f);
        float dlt  = u - mean;
        float sc   = 1.f + s;
        float x0 = fmaf(v[((size_t)n * 3 + 0) * FDIM + f], sc, dv[(size_t)n * F3 + f]);
        float x1 = fmaf(v[((size_t)n * 3 + 1) * FDIM + f], sc, dv[(size_t)n * F3 + FDIM + f]);
        float x2 = fmaf(v[((size_t)n * 3 + 2) * FDIM + f], sc, dv[(size_t)n * F3 + 2 * FDIM + f]);

        float var = dlt * dlt;
        float sq  = x0 * x0 + x1 * x1 + x2 * x2;
        block_reduce2_128(var, sq, sred);        // round 2: Σdlt² and Σ|x|²

        q[(size_t)n * FDIM + f] = dlt * rsqrtf(var * (1.f / 128.f) + 1e-5f) * g + bt;

        float inv = rsqrtf(sq * (1.f / 128.f) + 1e-8f);
        mu[((size_t)n * 3 + 0) * FDIM + f] = x0 * inv;
        mu[((size_t)n * 3 + 1) * FDIM + f] = x1 * inv;
        mu[((size_t)n * 3 + 2) * FDIM + f] = x2 * inv;
    }
}

// ---------------------------------------------------------------------------
extern "C" void kernel_launch(void* const* d_in, const int* in_sizes, int n_in,
                              void* d_out, int out_size, void* d_ws, size_t ws_size,
                              hipStream_t stream)
{
    const float* h     = (const float*)d_in[0];
    const float* v     = (const float*)d_in[1];
    const float* H     = (const float*)d_in[2];
    const float* V     = (const float*)d_in[3];
    const float* Wij   = (const float*)d_in[4];
    const float* dir   = (const float*)d_in[5];
    const float* W1    = (const float*)d_in[6];
    const float* b1    = (const float*)d_in[7];
    const float* W2    = (const float*)d_in[8];
    const float* b2    = (const float*)d_in[9];
    const float* Wmix  = (const float*)d_in[10];
    const float* Whr   = (const float*)d_in[11];
    const float* Whf   = (const float*)d_in[12];
    const float* Wvr   = (const float*)d_in[13];
    const float* gamma = (const float*)d_in[14];
    const float* beta  = (const float*)d_in[15];
    const int*   idx_i = (const int*)d_in[16];
    const int*   idx_j = (const int*)d_in[17];

    const int N = in_sizes[0] / FDIM;
    const int E = in_sizes[16];

    float* ws  = (float*)d_ws;
    float* X   = ws;                         // N*384
    float* ctx = X   + (size_t)N * F3;       // N*128
    float* dh  = ctx + (size_t)N * FDIM;     // N*128
    float* dv  = dh  + (size_t)N * FDIM;     // N*384
    int*   seg = (int*)(dv + (size_t)N * F3);// N+1

    float* q   = (float*)d_out;              // N*128
    float* mu  = q + (size_t)N * FDIM;       // N*384

    hipLaunchKernelGGL(k0_seg, dim3((N + 256) / 256), dim3(256), 0, stream,
                       idx_i, seg, E, N);
    hipLaunchKernelGGL(k12_ctxnet_mix, dim3((N + K1_R - 1) / K1_R), dim3(128), 0, stream,
                       H, W1, b1, W2, b2, v, Wmix, X, ctx, N);
    hipLaunchKernelGGL(k3_edges, dim3(N), dim3(256), 0, stream,
                       X, V, Wij, dir, seg, idx_j, dh, dv);
    hipLaunchKernelGGL(k4_epilogue, dim3((N + K4_R - 1) / K4_R), dim3(128), 0, stream,
                       h, v, dh, dv, ctx, Whr, Whf, Wvr, gamma, beta, q, mu, N);
}